// Round 18
// baseline (228.726 us; speedup 1.0000x reference)
//
#include <hip/hip_runtime.h>
#include <hip/hip_bf16.h>

// (B,N,D) = (4,4096,256) fp32 in/out.
//  wsplit:  W fp32 -> (wh, wl) fp16 (verified R16/17).
//  proj3:   fused q/k/v projection; Q,K write MFMA-fragment planes directly,
//           V linear; Q pre-scaled by log2e (verified R17).
//  vfrag_make: v -> vfrag (verified R16/17).
//  attn_sk: SPLIT-K flash attention, QBLK=64. Row-group J (64 rows) is
//           handled by TWO blocks (h=0,1) taking interleaved 128-key tiles
//           -> K/V cache traffic HALVED vs QBLK=32 (R17 analysis: 1.1GB at
//           ~11 TB/s L3 was ~the binder) while keeping 512 blocks = 2/CU
//           (the verified 4-wave/244-VGPR/co-residency config).
//           Each block writes fp16 normalized partial (o/l) + (m,l) fp32.
//  combine: exact 2-way softmax merge -> fp32 out (~96MB traffic).

#define SEQ   4096
#define DIM   256
#define LOG2E 1.4426950408889634f

typedef _Float16 f16;
typedef __attribute__((ext_vector_type(8)))  f16    f16x8;
typedef __attribute__((ext_vector_type(16))) float  f32x16;

// ---------------------------------------------------------------------------
// W fp32 [256][256] -> wh, wl fp16. blockIdx.y selects which W. (verified)
// ---------------------------------------------------------------------------
__global__ __launch_bounds__(256) void wsplit(
    const float* __restrict__ Wq, const float* __restrict__ Wk,
    const float* __restrict__ Wv, f16* __restrict__ whq, f16* __restrict__ wlq,
    f16* __restrict__ whk, f16* __restrict__ wlk,
    f16* __restrict__ whv, f16* __restrict__ wlv)
{
    const float* W; f16* wh; f16* wl;
    if (blockIdx.y == 0)      { W = Wq; wh = whq; wl = wlq; }
    else if (blockIdx.y == 1) { W = Wk; wh = whk; wl = wlk; }
    else                      { W = Wv; wh = whv; wl = wlv; }
    const int i = blockIdx.x * 256 + threadIdx.x;
    const float w = W[i];
    const f16 h = (f16)w;
    wh[i] = h;
    wl[i] = (f16)(w - (float)h);
}

// ---------------------------------------------------------------------------
// Fused projection (verified R17). Q,K -> fragment planes; V -> linear.
// ---------------------------------------------------------------------------
__global__ __launch_bounds__(256) void proj3(
    const float* __restrict__ X,
    const f16* __restrict__ Whq, const f16* __restrict__ Wlq, const float* __restrict__ bq,
    const f16* __restrict__ Whk, const f16* __restrict__ Wlk, const float* __restrict__ bk,
    const f16* __restrict__ Whv, const f16* __restrict__ Wlv, const float* __restrict__ bv,
    f16* __restrict__ outq, f16* __restrict__ outk, f16* __restrict__ outv)
{
    const f16* Wh; const f16* Wl; const float* bias; f16* out; float scale;
    if (blockIdx.y == 0)      { Wh = Whq; Wl = Wlq; bias = bq; out = outq; scale = LOG2E; }
    else if (blockIdx.y == 1) { Wh = Whk; Wl = Wlk; bias = bk; out = outk; scale = 1.f; }
    else                      { Wh = Whv; Wl = Wlv; bias = bv; out = outv; scale = 1.f; }

    const int w = threadIdx.x >> 6, lane = threadIdx.x & 63;
    const int col = lane & 31, hi = lane >> 5;
    const int m0 = blockIdx.x * 64 + (w & 1) * 32;
    const int e0 = (w >> 1) * 128;

    f32x16 acc[4] = {};
    for (int s = 0; s < 16; ++s) {
        const float* xp = X + (size_t)(m0 + col) * DIM + s * 16 + 8 * hi;
        float xv[8];
        *(float4*)&xv[0] = *(const float4*)xp;
        *(float4*)&xv[4] = *(const float4*)(xp + 4);
        f16x8 xh, xl;
        #pragma unroll
        for (int i = 0; i < 8; ++i) {
            xh[i] = (f16)xv[i];
            xl[i] = (f16)(xv[i] - (float)xh[i]);
        }
        #pragma unroll
        for (int c = 0; c < 4; ++c) {
            const size_t wo = (size_t)(e0 + c * 32 + col) * DIM + s * 16 + 8 * hi;
            const f16x8 wh = *(const f16x8*)(Wh + wo);
            const f16x8 wl = *(const f16x8*)(Wl + wo);
            acc[c] = __builtin_amdgcn_mfma_f32_32x32x16_f16(xh, wh, acc[c], 0, 0, 0);
            acc[c] = __builtin_amdgcn_mfma_f32_32x32x16_f16(xl, wh, acc[c], 0, 0, 0);
            acc[c] = __builtin_amdgcn_mfma_f32_32x32x16_f16(xh, wl, acc[c], 0, 0, 0);
        }
    }

    if (blockIdx.y < 2) {
        const int bb = m0 >> 12;
        const int m0loc = m0 & 4095;
        f16* fp = out + (size_t)bb * SEQ * DIM + (size_t)(m0loc >> 5) * 8192;
        #pragma unroll
        for (int c = 0; c < 4; ++c) {
            const int e = e0 + c * 32 + col;
            const float b = bias[e];
            const int eo = (e >> 4) * 512 + ((e >> 3) & 1) * 256 + (e & 7);
            #pragma unroll
            for (int r = 0; r < 16; ++r) {
                const int qr = (r & 3) + 8 * (r >> 2) + 4 * hi;
                fp[eo + qr * 8] = (f16)((acc[c][r] + b) * scale);
            }
        }
    } else {
        #pragma unroll
        for (int c = 0; c < 4; ++c) {
            const int e = e0 + c * 32 + col;
            const float b = bias[e];
            #pragma unroll
            for (int r = 0; r < 16; ++r) {
                const int m = m0 + (r & 3) + 8 * (r >> 2) + 4 * hi;
                out[(size_t)m * DIM + e] = (f16)(acc[c][r] + b);
            }
        }
    }
}

// ---------------------------------------------------------------------------
// vfrag_make: v [4096][256] -> vfrag (verified R16/17).
// ---------------------------------------------------------------------------
__global__ __launch_bounds__(256) void vfrag_make(
    const f16* __restrict__ v, uint4* __restrict__ dst)
{
    __shared__ f16 ldsT[32][136];
    const int kb = blockIdx.x, db = blockIdx.y, b = blockIdx.z;
    const uint4* v4 = (const uint4*)(v + (size_t)b * SEQ * DIM);
    uint4* d4 = dst + (size_t)b * 131072 + (size_t)(8 * kb + db) * 512;
    const int tau = threadIdx.x;

    #pragma unroll
    for (int ii = 0; ii < 2; ++ii) {
        const int e = tau + 256 * ii;
        const int r = e >> 2, ch = e & 3;
        const uint4 u = v4[(size_t)(128 * kb + r) * 32 + db * 4 + ch];
        const f16* uf = (const f16*)&u;
        #pragma unroll
        for (int i = 0; i < 8; ++i) ldsT[8 * ch + i][r] = uf[i];
    }
    __syncthreads();
    #pragma unroll
    for (int ii = 0; ii < 2; ++ii) {
        const int e = tau + 256 * ii;
        const int sl = e >> 6, l = e & 63;
        d4[e] = *(const uint4*)&ldsT[l & 31][16 * sl + 8 * (l >> 5)];
    }
}

// ---------------------------------------------------------------------------
// attn_sk: split-K flash. Block (b, J, h): rows [64J, 64J+64), tiles t = h,
// h+2, ... < T = (J+2)>>1. Waves: sub = wid>>1 (32-row half), kw = wid&1
// (64-key half of tile / 128-col half of output).
// Partial plane id pj2 = ((b*64+J)*2+h): part fp16 [64][256] = o/l;
// pml fp32 [2][64] = (m_log2, l).
// ---------------------------------------------------------------------------
__global__ __launch_bounds__(256, 1) void attn_sk(
    const uint4* __restrict__ qfrag, const uint4* __restrict__ kfrag,
    const uint4* __restrict__ vfrag, f16* __restrict__ part,
    float* __restrict__ pml, int nb)
{
    __shared__ uint4 Pex[2][2][512];         // [pbuf][sub], 8 slices, 32 KB
    __shared__ float mlbuf[2][2][2][2][32];  // [pbuf][sub][m|l][kw][q]

    int J, b, h;
    if (nb == 4) {
        const int lin = blockIdx.x;          // 512 blocks = 2/CU
        const int x = lin & 7;               // XCD
        b = x >> 1;
        h = x & 1;
        const int k = lin >> 3;              // k and k+32 share a CU
        J = (k < 32) ? k : (95 - k);         // J + J' = 63 -> const work
    } else { J = blockIdx.x >> 1; h = blockIdx.x & 1; b = 0; }

    const uint4* qfb = qfrag + (size_t)b * 131072;
    const uint4* kfb = kfrag + (size_t)b * 131072;
    const uint4* vfb = vfrag + (size_t)b * 131072;
    const int pj2 = (b * 64 + J) * 2 + h;
    f16* po = part + (size_t)pj2 * 16384;
    float* pm = pml + (size_t)pj2 * 128;

    const int wid = threadIdx.x >> 6, lane = threadIdx.x & 63;
    const int col = lane & 31, hi = lane >> 5;
    const int sub = wid >> 1, kw = wid & 1;
    const int q0w = 64 * J + 32 * sub;
    const int qmax = q0w + col;
    const int T = (J + 2) >> 1;              // 128-key tiles (total)

    // Q fragments resident (coalesced from qfrag; rows group = 2J+sub)
    f16x8 qhf[16];
    {
        const uint4* qp = qfb + (size_t)(2 * J + sub) * 1024 + lane;
        #pragma unroll
        for (int sl = 0; sl < 16; ++sl)
            qhf[sl] = __builtin_bit_cast(f16x8, qp[sl * 64]);
    }

    float m_run = -1e28f, l_run = 0.f;
    f32x16 oacc[4] = {};                     // cols 128*kw + 32*cg + col
    int it = 0;

    for (int t = h; t < T; t += 2, ++it) {
        const int pb = it & 1;

        // ---- QK^T: own 64-key half (2 groups of 32), parity chains ----
        const uint4* kp0 = kfb + (size_t)(4 * t + 2 * kw) * 1024 + lane;
        const uint4* kp1 = kp0 + 1024;
        f32x16 s0a = {}, s0b = {}, s1a = {}, s1b = {};
        __builtin_amdgcn_s_setprio(1);
        #pragma unroll
        for (int sl = 0; sl < 16; ++sl) {
            const f16x8 k0 = __builtin_bit_cast(f16x8, kp0[sl * 64]);
            const f16x8 k1 = __builtin_bit_cast(f16x8, kp1[sl * 64]);
            if (sl & 1) {
                s0b = __builtin_amdgcn_mfma_f32_32x32x16_f16(k0, qhf[sl], s0b, 0, 0, 0);
                s1b = __builtin_amdgcn_mfma_f32_32x32x16_f16(k1, qhf[sl], s1b, 0, 0, 0);
            } else {
                s0a = __builtin_amdgcn_mfma_f32_32x32x16_f16(k0, qhf[sl], s0a, 0, 0, 0);
                s1a = __builtin_amdgcn_mfma_f32_32x32x16_f16(k1, qhf[sl], s1a, 0, 0, 0);
            }
        }
        __builtin_amdgcn_s_setprio(0);

        // ---- mask + wave-local softmax over 64 keys ----
        float sv[32];
        float pmax = -1e30f, tsum = 0.f;
        #pragma unroll
        for (int r = 0; r < 16; ++r) {
            const int kr = (r & 3) + 8 * (r >> 2) + 4 * hi;
            const int kg0 = 128 * t + 64 * kw + kr;
            const float x0 = (kg0 <= qmax)      ? (s0a[r] + s0b[r]) : -1e30f;
            const float x1 = (kg0 + 32 <= qmax) ? (s1a[r] + s1b[r]) : -1e30f;
            sv[r] = x0; sv[16 + r] = x1;
            pmax = fmaxf(pmax, fmaxf(x0, x1));
        }
        pmax = fmaxf(pmax, __shfl_xor(pmax, 32));
        pmax = fmaxf(pmax, -1e28f);          // fully-masked half -> p = 0
        {
            float p[32];
            #pragma unroll
            for (int r = 0; r < 32; ++r) {
                p[r] = exp2f(sv[r] - pmax);
                tsum += p[r];
            }
            tsum += __shfl_xor(tsum, 32);
            // A-frag build x2 (verified cvt_pk + shfl_xor(32)); slices 4kw+0..3
            #pragma unroll
            for (int gg = 0; gg < 2; ++gg) {
                uint32_t Wd[8], Od[8];
                #pragma unroll
                for (int jj = 0; jj < 8; ++jj)
                    Wd[jj] = __builtin_bit_cast(uint32_t,
                        __builtin_amdgcn_cvt_pkrtz(p[16 * gg + 2 * jj], p[16 * gg + 2 * jj + 1]));
                #pragma unroll
                for (int jj = 0; jj < 8; ++jj)
                    Od[jj] = (uint32_t)__shfl_xor((int)Wd[jj], 32);
                uint4 A0, A1;
                if (hi == 0) {
                    A0.x = Wd[0]; A0.y = Wd[1]; A0.z = Od[0]; A0.w = Od[1];
                    A1.x = Wd[4]; A1.y = Wd[5]; A1.z = Od[4]; A1.w = Od[5];
                } else {
                    A0.x = Od[2]; A0.y = Od[3]; A0.z = Wd[2]; A0.w = Wd[3];
                    A1.x = Od[6]; A1.y = Od[7]; A1.z = Wd[6]; A1.w = Wd[7];
                }
                const int sb = 4 * kw + 2 * gg;
                Pex[pb][sub][((sb + 0) * 2 + hi) * 32 + col] = A0;
                Pex[pb][sub][((sb + 1) * 2 + hi) * 32 + col] = A1;
            }
        }
        if (lane < 32) {
            mlbuf[pb][sub][0][kw][col] = pmax;
            mlbuf[pb][sub][1][kw][col] = tsum;
        }
        __syncthreads();                     // the ONLY barrier per iter

        // ---- 2-way m/l merge, defer-max rescale ----
        const float mw0 = mlbuf[pb][sub][0][0][col], mw1 = mlbuf[pb][sub][0][1][col];
        const float tw0 = mlbuf[pb][sub][1][0][col], tw1 = mlbuf[pb][sub][1][1][col];
        const float mt = fmaxf(mw0, mw1);
        float scale = 1.f;
        if (__any(mt > m_run + 11.5415603f)) {   // 8-nat window (log2)
            const float m_new = fmaxf(m_run, mt);
            scale = exp2f(m_run - m_new);
            m_run = m_new;
            #pragma unroll
            for (int r = 0; r < 16; ++r) {
                const int qr = (r & 3) + 8 * (r >> 2) + 4 * hi;
                const float scr = __shfl(scale, qr | (lane & 32));
                oacc[0][r] *= scr; oacc[1][r] *= scr;
                oacc[2][r] *= scr; oacc[3][r] *= scr;
            }
        }
        const float c0 = exp2f(mw0 - m_run), c1 = exp2f(mw1 - m_run);
        l_run = l_run * scale + tw0 * c0 + tw1 * c1;
        const f16 ch[2] = {(f16)c0, (f16)c1};

        // ---- PV: af preloaded once, 4 col-groups (own 128-col half) ----
        f16x8 af[8];
        #pragma unroll
        for (int s = 0; s < 8; ++s) {
            f16x8 a = __builtin_bit_cast(f16x8, Pex[pb][sub][(s * 2 + hi) * 32 + col]);
            af[s] = a * ch[s >> 2];          // producer-kw correction
        }
        __builtin_amdgcn_s_setprio(1);
        #pragma unroll
        for (int cg = 0; cg < 4; ++cg) {
            const uint4* vp = vfb + (size_t)(8 * t + 4 * kw + cg) * 512 + lane;
            f16x8 vf[8];
            #pragma unroll
            for (int s = 0; s < 8; ++s) vf[s] = __builtin_bit_cast(f16x8, vp[s * 64]);
            #pragma unroll
            for (int s = 0; s < 8; ++s)
                oacc[cg] = __builtin_amdgcn_mfma_f32_32x32x16_f16(af[s], vf[s], oacc[cg], 0, 0, 0);
        }
        __builtin_amdgcn_s_setprio(0);
        // dbuf: next iter uses Pex[pb^1]; barrier(it+1) orders Pex[pb] reuse.
    }

    // ---- epilogue: write normalized fp16 partial + (m,l) ----
    const float linv = (l_run > 0.f) ? (1.f / l_run) : 0.f;
    if (kw == 0 && lane < 32) {
        pm[32 * sub + col] = m_run;          // per-row (q = col)
        pm[64 + 32 * sub + col] = l_run;
    }
    #pragma unroll
    for (int r = 0; r < 16; ++r) {
        const int qr = (r & 3) + 8 * (r >> 2) + 4 * hi;
        const float lr = __shfl(linv, qr | (lane & 32));
        const int row = 32 * sub + qr;
        #pragma unroll
        for (int cg = 0; cg < 4; ++cg)
            po[row * 256 + 128 * kw + 32 * cg + col] = (f16)(oacc[cg][r] * lr);
    }
}

// ---------------------------------------------------------------------------
// combine: out = (a0*o0 + a1*o1) / (a0+a1), ai = 2^(mi-M) * li.
// One block per (b,J): 64 rows x 256 cols; thread t = col.
// ---------------------------------------------------------------------------
__global__ __launch_bounds__(256) void combine(
    const f16* __restrict__ part, const float* __restrict__ pml,
    float* __restrict__ out)
{
    const int pj = blockIdx.x;               // b*64 + J
    const f16* o0 = part + (size_t)(2 * pj) * 16384;
    const f16* o1 = part + (size_t)(2 * pj + 1) * 16384;
    const float* q0 = pml + (size_t)(2 * pj) * 128;
    const float* q1 = pml + (size_t)(2 * pj + 1) * 128;
    float* op = out + (size_t)pj * 64 * 256; // rows contiguous: b*4096+64J
    const int t = threadIdx.x;

    for (int r = 0; r < 64; ++r) {
        const float m0 = q0[r], l0 = q0[64 + r];
        const float m1 = q1[r], l1 = q1[64 + r];
        const float M = fmaxf(m0, m1);
        const float a0 = exp2f(m0 - M) * l0;
        const float a1 = exp2f(m1 - M) * l1;
        const float inv = 1.f / (a0 + a1);
        const float w0 = a0 * inv, w1 = a1 * inv;
        op[r * 256 + t] = w0 * (float)o0[r * 256 + t] + w1 * (float)o1[r * 256 + t];
    }
}

// ---------------------------------------------------------------------------
extern "C" void kernel_launch(void* const* d_in, const int* in_sizes, int n_in,
                              void* d_out, int out_size, void* d_ws, size_t ws_size,
                              hipStream_t stream) {
    const float* x  = (const float*)d_in[0];
    const float* Wq = (const float*)d_in[1];
    const float* bq = (const float*)d_in[2];
    const float* Wk = (const float*)d_in[3];
    const float* bk = (const float*)d_in[4];
    const float* Wv = (const float*)d_in[5];
    const float* bv = (const float*)d_in[6];
    float* out = (float*)d_out;

    const size_t PP = (size_t)SEQ * DIM;            // 1M elems per batch plane
    const size_t FULL = 4 * PP;                     // 4M elems (8 MB fp16)
    const size_t WSZ = (size_t)DIM * DIM;           // 64K elems per W plane

    if (ws_size >= FULL * 2 * 5) {                  // known-true threshold
        f16* qfr = (f16*)d_ws;                      // Q fragment plane (8 MB)
        f16* kfr = qfr + FULL;                      // K fragment plane (8 MB)
        f16* vv  = kfr + FULL;                      // V linear (8 MB)
        f16* vfr = vv + FULL;                       // V fragment plane (8 MB)
        f16* prt = vfr + FULL;                      // partials: 512*16384 f16 = 16 MB
        f16* pmlp = prt + (size_t)512 * 16384;      // 512*128 f32 = 256 KB
        f16* wsp = pmlp + (size_t)512 * 128 * 2;    // 6 x 64K fp16 = 768 KB
        f16* whq = wsp;          f16* wlq = whq + WSZ;
        f16* whk = wlq + WSZ;    f16* wlk = whk + WSZ;
        f16* whv = wlk + WSZ;    f16* wlv = whv + WSZ;

        wsplit<<<dim3(256, 3), 256, 0, stream>>>(Wq, Wk, Wv, whq, wlq, whk, wlk, whv, wlv);
        proj3<<<dim3(256, 3), 256, 0, stream>>>(
            x, whq, wlq, bq, whk, wlk, bk, whv, wlv, bv, qfr, kfr, vv);
        vfrag_make<<<dim3(32, 8, 4), 256, 0, stream>>>(vv, (uint4*)vfr);
        attn_sk<<<dim3(512), 256, 0, stream>>>(
            (const uint4*)qfr, (const uint4*)kfr, (const uint4*)vfr,
            prt, (float*)pmlp, 4);
        combine<<<dim3(256), 256, 0, stream>>>(prt, (const float*)pmlp, out);
    } else {
        // per-batch fallback
        f16* qfr = (f16*)d_ws;
        f16* kfr = qfr + PP;
        f16* vv  = kfr + PP;
        f16* vfr = vv + PP;
        f16* prt = vfr + PP;                        // 128*16384 f16 = 4 MB
        f16* pmlp = prt + (size_t)128 * 16384;      // 128*128 f32
        f16* wsp = pmlp + (size_t)128 * 128 * 2;
        f16* whq = wsp;          f16* wlq = whq + WSZ;
        f16* whk = wlq + WSZ;    f16* wlk = whk + WSZ;
        f16* whv = wlk + WSZ;    f16* wlv = whv + WSZ;

        wsplit<<<dim3(256, 3), 256, 0, stream>>>(Wq, Wk, Wv, whq, wlq, whk, wlk, whv, wlv);
        for (int b = 0; b < 4; ++b) {
            const float* xb = x + b * PP;
            proj3<<<dim3(64, 3), 256, 0, stream>>>(
                xb, whq, wlq, bq, whk, wlk, bk, whv, wlv, bv, qfr, kfr, vv);
            vfrag_make<<<dim3(32, 8, 1), 256, 0, stream>>>(vv, (uint4*)vfr);
            attn_sk<<<dim3(128), 256, 0, stream>>>(
                (const uint4*)qfr, (const uint4*)kfr, (const uint4*)vfr,
                prt, (float*)pmlp, 1);
            combine<<<dim3(64), 256, 0, stream>>>(prt, (const float*)pmlp, out + b * PP);
        }
    }
}

// Round 19
// 160.631 us; speedup vs baseline: 1.4239x; 1.4239x over previous
//
#include <hip/hip_runtime.h>
#include <hip/hip_bf16.h>

// (B,N,D) = (4,4096,256) fp32 in/out.  3-launch pipeline:
//  wsplit_h: W fp32 -> wh fp16 (2-term split needs no wl planes).
//  proj3:    fused q/k/v projection, 2-TERM fp16 split ((xh+xl)*wh — W-round
//            error ~3e-3 nats in scores, well inside budget).
//            Q,K -> MFMA-fragment planes (verified R17/18 epilogue);
//            V -> vfrag DIRECTLY via LDS-transpose epilogue (index algebra =
//            verified vfrag_make definition, re-derived; kills a launch +
//            16 MB round-trip). Q pre-scaled by log2e.
//  attn_flash13: the verified 100 µs R15/R16 attention body (no K-prefetch —
//            proven neutral; Q coalesced from qfrag; vfB pre-barrier) +
//            s_setprio around QK^T/PV MFMA clusters (m191: helps when the
//            2 co-resident blocks/CU are at different phases).
//            512 blocks x 256 thr (4 waves -> big VGPR budget), K/V from
//            fragment-ordered global, LDS = dbuf Pex + mlbuf, 1 barrier/iter,
//            R14 co-residency pairing (f(k)+f(k+32)=63).

#define SEQ   4096
#define DIM   256
#define LOG2E 1.4426950408889634f

typedef _Float16 f16;
typedef __attribute__((ext_vector_type(8)))  f16    f16x8;
typedef __attribute__((ext_vector_type(16))) float  f32x16;

// ---------------------------------------------------------------------------
// W fp32 [256][256] -> wh fp16. blockIdx.y selects which W.
// ---------------------------------------------------------------------------
__global__ __launch_bounds__(256) void wsplit_h(
    const float* __restrict__ Wq, const float* __restrict__ Wk,
    const float* __restrict__ Wv, f16* __restrict__ whq,
    f16* __restrict__ whk, f16* __restrict__ whv)
{
    const float* W; f16* wh;
    if (blockIdx.y == 0)      { W = Wq; wh = whq; }
    else if (blockIdx.y == 1) { W = Wk; wh = whk; }
    else                      { W = Wv; wh = whv; }
    const int i = blockIdx.x * 256 + threadIdx.x;
    wh[i] = (f16)W[i];
}

// ---------------------------------------------------------------------------
// Fused projection, 2-term. blockIdx.y: 0=Q (frag, log2e), 1=K (frag),
// 2=V (vfrag via LDS transpose).
// Q/K frag layout (verified R17/18): f16 idx in batch plane =
//   (mloc>>5)*8192 + (e>>4)*512 + ((e>>3)&1)*256 + (mloc&31)*8 + (e&7)
// vfrag (verified R15-R18 definition): uint4 (8kb+db)*512 + sl*64 + l packs
//   f16 j: v[128kb + 16sl + 8(l>>5) + j][32db + (l&31)]
// ---------------------------------------------------------------------------
__global__ __launch_bounds__(256) void proj3(
    const float* __restrict__ X,
    const f16* __restrict__ Whq, const float* __restrict__ bq,
    const f16* __restrict__ Whk, const float* __restrict__ bk,
    const f16* __restrict__ Whv, const float* __restrict__ bv,
    f16* __restrict__ outq, f16* __restrict__ outk, f16* __restrict__ outv)
{
    __shared__ f16 vtile[64][264];           // V transpose tile (33.8 KB)

    const f16* Wh; const float* bias; float scale;
    if (blockIdx.y == 0)      { Wh = Whq; bias = bq; scale = LOG2E; }
    else if (blockIdx.y == 1) { Wh = Whk; bias = bk; scale = 1.f; }
    else                      { Wh = Whv; bias = bv; scale = 1.f; }

    const int w = threadIdx.x >> 6, lane = threadIdx.x & 63;
    const int col = lane & 31, hi = lane >> 5;
    const int m0 = blockIdx.x * 64 + (w & 1) * 32;
    const int e0 = (w >> 1) * 128;

    f32x16 acc[4] = {};
    for (int s = 0; s < 16; ++s) {
        const float* xp = X + (size_t)(m0 + col) * DIM + s * 16 + 8 * hi;
        float xv[8];
        *(float4*)&xv[0] = *(const float4*)xp;
        *(float4*)&xv[4] = *(const float4*)(xp + 4);
        f16x8 xh, xl;
        #pragma unroll
        for (int i = 0; i < 8; ++i) {
            xh[i] = (f16)xv[i];
            xl[i] = (f16)(xv[i] - (float)xh[i]);
        }
        #pragma unroll
        for (int c = 0; c < 4; ++c) {
            const size_t wo = (size_t)(e0 + c * 32 + col) * DIM + s * 16 + 8 * hi;
            const f16x8 wh = *(const f16x8*)(Wh + wo);
            acc[c] = __builtin_amdgcn_mfma_f32_32x32x16_f16(xh, wh, acc[c], 0, 0, 0);
            acc[c] = __builtin_amdgcn_mfma_f32_32x32x16_f16(xl, wh, acc[c], 0, 0, 0);
        }
    }

    if (blockIdx.y < 2) {
        // fragment-layout epilogue (Q, K) — verified R17/R18
        const int bb = m0 >> 12;
        const int m0loc = m0 & 4095;
        f16* fp = (blockIdx.y == 0 ? outq : outk)
                  + (size_t)bb * SEQ * DIM + (size_t)(m0loc >> 5) * 8192;
        #pragma unroll
        for (int c = 0; c < 4; ++c) {
            const int e = e0 + c * 32 + col;
            const float b = bias[e];
            const int eo = (e >> 4) * 512 + ((e >> 3) & 1) * 256 + (e & 7);
            #pragma unroll
            for (int r = 0; r < 16; ++r) {
                const int qr = (r & 3) + 8 * (r >> 2) + 4 * hi;
                fp[eo + qr * 8] = (f16)((acc[c][r] + b) * scale);
            }
        }
    } else {
        // V epilogue: vtile[keyrel][dim] then vfrag-ordered store
        #pragma unroll
        for (int c = 0; c < 4; ++c) {
            const int e = e0 + c * 32 + col;
            const float b = bias[e];
            #pragma unroll
            for (int r = 0; r < 16; ++r) {
                const int qr = (r & 3) + 8 * (r >> 2) + 4 * hi;
                vtile[32 * (w & 1) + qr][e] = (f16)(acc[c][r] + b);
            }
        }
        __syncthreads();
        const int bb   = blockIdx.x >> 6;          // batch (64 blocks/batch)
        const int kb   = (blockIdx.x & 63) >> 1;   // 128-key block
        const int half = blockIdx.x & 1;           // keys 64*half..+63
        uint4* vout = (uint4*)outv + (size_t)bb * 131072;
        const int tid = threadIdx.x;
        const int slr = tid >> 6, l = tid & 63;
        const int row = 16 * slr + 8 * (l >> 5);
        #pragma unroll
        for (int i = 0; i < 8; ++i) {              // i = db (dim block)
            f16 tmp[8];
            #pragma unroll
            for (int j = 0; j < 8; ++j)
                tmp[j] = vtile[row + j][32 * i + (l & 31)];
            vout[(size_t)(8 * kb + i) * 512 + (4 * half + slr) * 64 + l] =
                *(const uint4*)tmp;
        }
    }
}

// ---------------------------------------------------------------------------
// attn_flash13: verified R15/R16 attention + setprio + qfrag Q loads.
// ---------------------------------------------------------------------------
__global__ __launch_bounds__(256, 1) void attn_flash13(
    const uint4* __restrict__ qfrag, const uint4* __restrict__ kfrag,
    const uint4* __restrict__ vfrag, float* __restrict__ out, int nb)
{
    __shared__ uint4 Pex[2][512];        // dbuf A-frags, 16 KB
    __shared__ float mlbuf[2][2][4][32]; // [buf][m|l][kq][q], 2 KB

    int qt, b;
    if (nb == 4) {
        const int lin = blockIdx.x;       // 512 blocks = 2/CU
        const int x = lin & 7;            // XCD
        b = x >> 1;                       // 2 XCDs per batch
        const int k = lin >> 3;           // slot k and k+32 share a CU
        const int f = (k < 32) ? k : (95 - k);   // f + f' = 63
        qt = 2 * f + (x & 1);             // [0,128)
    } else { qt = blockIdx.x; b = 0; }    // grid 128

    const size_t pp = (size_t)SEQ * DIM;
    const uint4* qfb = qfrag + (size_t)b * 131072;
    const uint4* kfb = kfrag + (size_t)b * 131072;
    const uint4* vfb = vfrag + (size_t)b * 131072;
    float* outb = out + b * pp;

    const int wid = threadIdx.x >> 6, lane = threadIdx.x & 63;
    const int col = lane & 31, hi = lane >> 5;
    const int kq = wid;                   // 32-key quarter / 64-col quarter
    const int q0 = qt * 32;
    const int nt = (qt + 4) >> 2;         // 128-key tiles

    // Q fragments resident, coalesced from qfrag (16 x 1KB)
    f16x8 qhf[16];
    {
        const uint4* qp = qfb + (size_t)(q0 >> 5) * 1024 + lane;
        #pragma unroll
        for (int sl = 0; sl < 16; ++sl)
            qhf[sl] = __builtin_bit_cast(f16x8, qp[sl * 64]);
    }

    float m_run = -1e28f, l_run = 0.f;
    f32x16 oacc[2] = {};                  // cols 64*kq + {col, 32+col}

    for (int t = 0; t < nt; ++t) {
        const int key0 = t << 7;
        const int pb = t & 1;
        const uint4* kp = kfb + (size_t)(4 * t + kq) * 1024 + lane;

        // ---- QK^T: own 32-key quarter (verified 2-chain form) ----
        f32x16 s1 = {}, s2 = {};
        __builtin_amdgcn_s_setprio(1);
        #pragma unroll
        for (int sl = 0; sl < 16; ++sl) {
            const f16x8 kf = __builtin_bit_cast(f16x8, kp[sl * 64]);
            if (sl & 1) s2 = __builtin_amdgcn_mfma_f32_32x32x16_f16(kf, qhf[sl], s2, 0, 0, 0);
            else        s1 = __builtin_amdgcn_mfma_f32_32x32x16_f16(kf, qhf[sl], s1, 0, 0, 0);
        }
        __builtin_amdgcn_s_setprio(0);

        // ---- V prefetch A-half (slices 0..3, own 64-col quarter) ----
        const uint4* vp = vfb + (size_t)(8 * t + 2 * kq) * 512 + lane;
        f16x8 vfA[2][4];
        #pragma unroll
        for (int cg = 0; cg < 2; ++cg)
            #pragma unroll
            for (int s = 0; s < 4; ++s)
                vfA[cg][s] = __builtin_bit_cast(f16x8, vp[cg * 512 + s * 64]);

        // ---- mask + wave-local softmax (verified R10-R16 verbatim) ----
        float sv[16];
        float pmax = -1e30f, tsum = 0.f;
        #pragma unroll
        for (int r = 0; r < 16; ++r) {
            const int kg = key0 + 32 * kq + (r & 3) + 8 * (r >> 2) + 4 * hi;
            const float x = (kg <= q0 + col) ? (s1[r] + s2[r]) : -1e30f;
            sv[r] = x;
            pmax = fmaxf(pmax, x);
        }
        pmax = fmaxf(pmax, __shfl_xor(pmax, 32));
        pmax = fmaxf(pmax, -1e28f);       // fully-masked quarter -> p = 0
        {
            float p[16];
            #pragma unroll
            for (int r = 0; r < 16; ++r) {
                p[r] = exp2f(sv[r] - pmax);
                tsum += p[r];
            }
            tsum += __shfl_xor(tsum, 32);
            // A-frag build (verified cvt_pk + shfl_xor(32))
            uint32_t Wd[8], Od[8];
            #pragma unroll
            for (int jj = 0; jj < 8; ++jj)
                Wd[jj] = __builtin_bit_cast(uint32_t,
                    __builtin_amdgcn_cvt_pkrtz(p[2 * jj], p[2 * jj + 1]));
            #pragma unroll
            for (int jj = 0; jj < 8; ++jj)
                Od[jj] = (uint32_t)__shfl_xor((int)Wd[jj], 32);
            uint4 A0, A1;
            if (hi == 0) {
                A0.x = Wd[0]; A0.y = Wd[1]; A0.z = Od[0]; A0.w = Od[1];
                A1.x = Wd[4]; A1.y = Wd[5]; A1.z = Od[4]; A1.w = Od[5];
            } else {
                A0.x = Od[2]; A0.y = Od[3]; A0.z = Wd[2]; A0.w = Wd[3];
                A1.x = Od[6]; A1.y = Od[7]; A1.z = Wd[6]; A1.w = Wd[7];
            }
            Pex[pb][((2 * kq + 0) * 2 + hi) * 32 + col] = A0;  // keys [32kq,+16)
            Pex[pb][((2 * kq + 1) * 2 + hi) * 32 + col] = A1;  // keys [32kq+16,+16)
        }
        if (lane < 32) {
            mlbuf[pb][0][kq][col] = pmax;
            mlbuf[pb][1][kq][col] = tsum;
        }

        // ---- V prefetch B-half (slices 4..7) BEFORE the barrier ----
        f16x8 vfB[2][4];
        #pragma unroll
        for (int cg = 0; cg < 2; ++cg)
            #pragma unroll
            for (int s = 0; s < 4; ++s)
                vfB[cg][s] = __builtin_bit_cast(f16x8, vp[cg * 512 + (s + 4) * 64]);

        __syncthreads();                  // the ONLY barrier per iter

        // ---- 4-way m/l merge (verified), defer-max rescale ----
        const float mw0 = mlbuf[pb][0][0][col], mw1 = mlbuf[pb][0][1][col];
        const float mw2 = mlbuf[pb][0][2][col], mw3 = mlbuf[pb][0][3][col];
        const float tw0 = mlbuf[pb][1][0][col], tw1 = mlbuf[pb][1][1][col];
        const float tw2 = mlbuf[pb][1][2][col], tw3 = mlbuf[pb][1][3][col];
        const float mt = fmaxf(fmaxf(mw0, mw1), fmaxf(mw2, mw3));
        float scale = 1.f;
        if (__any(mt > m_run + 11.5415603f)) {   // 8-nat window (log2)
            const float m_new = fmaxf(m_run, mt);
            scale = exp2f(m_run - m_new);
            m_run = m_new;
            #pragma unroll
            for (int r = 0; r < 16; ++r) {
                const int qr = (r & 3) + 8 * (r >> 2) + 4 * hi;
                const float scr = __shfl(scale, qr | (lane & 32));
                oacc[0][r] *= scr; oacc[1][r] *= scr;
            }
        }
        const float c0 = exp2f(mw0 - m_run), c1 = exp2f(mw1 - m_run);
        const float c2 = exp2f(mw2 - m_run), c3 = exp2f(mw3 - m_run);
        l_run = l_run * scale + tw0 * c0 + tw1 * c1 + tw2 * c2 + tw3 * c3;
        const f16 ch[4] = {(f16)c0, (f16)c1, (f16)c2, (f16)c3};

        // ---- PV: 8 slices x own 64-col quarter (V in regs) ----
        __builtin_amdgcn_s_setprio(1);
        #pragma unroll
        for (int s4 = 0; s4 < 4; ++s4) {
            f16x8 af = __builtin_bit_cast(f16x8, Pex[pb][(s4 * 2 + hi) * 32 + col]);
            af = af * ch[s4 >> 1];
            oacc[0] = __builtin_amdgcn_mfma_f32_32x32x16_f16(af, vfA[0][s4], oacc[0], 0, 0, 0);
            oacc[1] = __builtin_amdgcn_mfma_f32_32x32x16_f16(af, vfA[1][s4], oacc[1], 0, 0, 0);
        }
        #pragma unroll
        for (int s4 = 0; s4 < 4; ++s4) {
            f16x8 af = __builtin_bit_cast(f16x8, Pex[pb][((s4 + 4) * 2 + hi) * 32 + col]);
            af = af * ch[2 + (s4 >> 1)];
            oacc[0] = __builtin_amdgcn_mfma_f32_32x32x16_f16(af, vfB[0][s4], oacc[0], 0, 0, 0);
            oacc[1] = __builtin_amdgcn_mfma_f32_32x32x16_f16(af, vfB[1][s4], oacc[1], 0, 0, 0);
        }
        __builtin_amdgcn_s_setprio(0);
        // dbuf: next iter writes Pex[pb^1]/mlbuf[pb^1]; laggard's reads of
        // Pex[pb] are safe; barrier(t+1) orders reuse of Pex[pb] at t+2.
    }

    // ---- epilogue: divide by l, store fp32 ----
    const float linv = 1.f / l_run;
    #pragma unroll
    for (int r = 0; r < 16; ++r) {
        const int qr = (r & 3) + 8 * (r >> 2) + 4 * hi;
        const float lr = __shfl(linv, qr | (lane & 32));
        const int n = q0 + qr;
        outb[(size_t)n * DIM + 64 * kq + col]      = oacc[0][r] * lr;
        outb[(size_t)n * DIM + 64 * kq + 32 + col] = oacc[1][r] * lr;
    }
}

// ---------------------------------------------------------------------------
extern "C" void kernel_launch(void* const* d_in, const int* in_sizes, int n_in,
                              void* d_out, int out_size, void* d_ws, size_t ws_size,
                              hipStream_t stream) {
    const float* x  = (const float*)d_in[0];
    const float* Wq = (const float*)d_in[1];
    const float* bq = (const float*)d_in[2];
    const float* Wk = (const float*)d_in[3];
    const float* bk = (const float*)d_in[4];
    const float* Wv = (const float*)d_in[5];
    const float* bv = (const float*)d_in[6];
    float* out = (float*)d_out;

    const size_t PP = (size_t)SEQ * DIM;            // 1M elems per batch plane
    const size_t FULL = 4 * PP;                     // 4M elems (8 MB fp16)
    const size_t WSZ = (size_t)DIM * DIM;           // 64K elems per W plane

    if (ws_size >= FULL * 2 * 5) {                  // known-true threshold
        f16* qfr = (f16*)d_ws;                      // Q fragment plane (8 MB)
        f16* kfr = qfr + FULL;                      // K fragment plane (8 MB)
        f16* vfr = kfr + FULL;                      // V fragment plane (8 MB)
        f16* whq = vfr + FULL;                      // 3 x 64K fp16 = 384 KB
        f16* whk = whq + WSZ;
        f16* whv = whk + WSZ;

        wsplit_h<<<dim3(256, 3), 256, 0, stream>>>(Wq, Wk, Wv, whq, whk, whv);
        proj3<<<dim3(256, 3), 256, 0, stream>>>(
            x, whq, bq, whk, bk, whv, bv, qfr, kfr, vfr);
        attn_flash13<<<dim3(512), 256, 0, stream>>>(
            (const uint4*)qfr, (const uint4*)kfr, (const uint4*)vfr, out, 4);
    } else {
        // per-batch fallback (~24.4 MB не needed; ~24.4/4)
        f16* qfr = (f16*)d_ws;
        f16* kfr = qfr + PP;
        f16* vfr = kfr + PP;
        f16* whq = vfr + PP;
        f16* whk = whq + WSZ;
        f16* whv = whk + WSZ;

        wsplit_h<<<dim3(256, 3), 256, 0, stream>>>(Wq, Wk, Wv, whq, whk, whv);
        for (int b = 0; b < 4; ++b) {
            const float* xb = x + b * PP;
            proj3<<<dim3(64, 3), 256, 0, stream>>>(
                xb, whq, bq, whk, bk, whv, bv, qfr, kfr, vfr);
            attn_flash13<<<dim3(128), 256, 0, stream>>>(
                (const uint4*)qfr, (const uint4*)kfr, (const uint4*)vfr, out + b * PP, 1);
        }
    }
}

// Round 20
// 126.177 us; speedup vs baseline: 1.8127x; 1.2731x over previous
//
#include <hip/hip_runtime.h>
#include <hip/hip_bf16.h>

// (B,N,D) = (4,4096,256) fp32 in/out.  3-launch pipeline:
//  wsplit_h: W fp32 -> wh fp16.
//  proj3:    fused q/k/v projection, 2-term fp16 split (verified R19,
//            absmax 0.047 vs 0.107 threshold). Q,K -> MFMA-fragment planes;
//            V -> vfrag directly (verified R19 epilogues). Q pre-scaled log2e.
//  attn_flash14: the verified ~100 µs R15/R16 attention body. R19's
//            s_setprio REMOVED — it cost +23 µs: with 4 barrier-synced
//            waves/block and 2 co-resident blocks, priority-boosting one
//            block's MFMA cluster starves the other's VALU phase (matches
//            m190: setprio hurts lockstep configs; m191's gain was for
//            independent 1-wave blocks).
//            512 blocks x 256 thr, K/V/Q from fragment-ordered global,
//            LDS = dbuf Pex + mlbuf, 1 barrier/iter, co-residency pairing.

#define SEQ   4096
#define DIM   256
#define LOG2E 1.4426950408889634f

typedef _Float16 f16;
typedef __attribute__((ext_vector_type(8)))  f16    f16x8;
typedef __attribute__((ext_vector_type(16))) float  f32x16;

// ---------------------------------------------------------------------------
// W fp32 [256][256] -> wh fp16. blockIdx.y selects which W.
// ---------------------------------------------------------------------------
__global__ __launch_bounds__(256) void wsplit_h(
    const float* __restrict__ Wq, const float* __restrict__ Wk,
    const float* __restrict__ Wv, f16* __restrict__ whq,
    f16* __restrict__ whk, f16* __restrict__ whv)
{
    const float* W; f16* wh;
    if (blockIdx.y == 0)      { W = Wq; wh = whq; }
    else if (blockIdx.y == 1) { W = Wk; wh = whk; }
    else                      { W = Wv; wh = whv; }
    const int i = blockIdx.x * 256 + threadIdx.x;
    wh[i] = (f16)W[i];
}

// ---------------------------------------------------------------------------
// Fused projection, 2-term (verified R19). blockIdx.y: 0=Q (frag, log2e),
// 1=K (frag), 2=V (vfrag via LDS transpose).
// ---------------------------------------------------------------------------
__global__ __launch_bounds__(256) void proj3(
    const float* __restrict__ X,
    const f16* __restrict__ Whq, const float* __restrict__ bq,
    const f16* __restrict__ Whk, const float* __restrict__ bk,
    const f16* __restrict__ Whv, const float* __restrict__ bv,
    f16* __restrict__ outq, f16* __restrict__ outk, f16* __restrict__ outv)
{
    __shared__ f16 vtile[64][264];           // V transpose tile (33.8 KB)

    const f16* Wh; const float* bias; float scale;
    if (blockIdx.y == 0)      { Wh = Whq; bias = bq; scale = LOG2E; }
    else if (blockIdx.y == 1) { Wh = Whk; bias = bk; scale = 1.f; }
    else                      { Wh = Whv; bias = bv; scale = 1.f; }

    const int w = threadIdx.x >> 6, lane = threadIdx.x & 63;
    const int col = lane & 31, hi = lane >> 5;
    const int m0 = blockIdx.x * 64 + (w & 1) * 32;
    const int e0 = (w >> 1) * 128;

    f32x16 acc[4] = {};
    for (int s = 0; s < 16; ++s) {
        const float* xp = X + (size_t)(m0 + col) * DIM + s * 16 + 8 * hi;
        float xv[8];
        *(float4*)&xv[0] = *(const float4*)xp;
        *(float4*)&xv[4] = *(const float4*)(xp + 4);
        f16x8 xh, xl;
        #pragma unroll
        for (int i = 0; i < 8; ++i) {
            xh[i] = (f16)xv[i];
            xl[i] = (f16)(xv[i] - (float)xh[i]);
        }
        #pragma unroll
        for (int c = 0; c < 4; ++c) {
            const size_t wo = (size_t)(e0 + c * 32 + col) * DIM + s * 16 + 8 * hi;
            const f16x8 wh = *(const f16x8*)(Wh + wo);
            acc[c] = __builtin_amdgcn_mfma_f32_32x32x16_f16(xh, wh, acc[c], 0, 0, 0);
            acc[c] = __builtin_amdgcn_mfma_f32_32x32x16_f16(xl, wh, acc[c], 0, 0, 0);
        }
    }

    if (blockIdx.y < 2) {
        // fragment-layout epilogue (Q, K) — verified R17-R19
        const int bb = m0 >> 12;
        const int m0loc = m0 & 4095;
        f16* fp = (blockIdx.y == 0 ? outq : outk)
                  + (size_t)bb * SEQ * DIM + (size_t)(m0loc >> 5) * 8192;
        #pragma unroll
        for (int c = 0; c < 4; ++c) {
            const int e = e0 + c * 32 + col;
            const float b = bias[e];
            const int eo = (e >> 4) * 512 + ((e >> 3) & 1) * 256 + (e & 7);
            #pragma unroll
            for (int r = 0; r < 16; ++r) {
                const int qr = (r & 3) + 8 * (r >> 2) + 4 * hi;
                fp[eo + qr * 8] = (f16)((acc[c][r] + b) * scale);
            }
        }
    } else {
        // V epilogue: vtile[keyrel][dim] then vfrag-ordered store (verified R19)
        #pragma unroll
        for (int c = 0; c < 4; ++c) {
            const int e = e0 + c * 32 + col;
            const float b = bias[e];
            #pragma unroll
            for (int r = 0; r < 16; ++r) {
                const int qr = (r & 3) + 8 * (r >> 2) + 4 * hi;
                vtile[32 * (w & 1) + qr][e] = (f16)(acc[c][r] + b);
            }
        }
        __syncthreads();
        const int bb   = blockIdx.x >> 6;          // batch (64 blocks/batch)
        const int kb   = (blockIdx.x & 63) >> 1;   // 128-key block
        const int half = blockIdx.x & 1;           // keys 64*half..+63
        uint4* vout = (uint4*)outv + (size_t)bb * 131072;
        const int tid = threadIdx.x;
        const int slr = tid >> 6, l = tid & 63;
        const int row = 16 * slr + 8 * (l >> 5);
        #pragma unroll
        for (int i = 0; i < 8; ++i) {              // i = db (dim block)
            f16 tmp[8];
            #pragma unroll
            for (int j = 0; j < 8; ++j)
                tmp[j] = vtile[row + j][32 * i + (l & 31)];
            vout[(size_t)(8 * kb + i) * 512 + (4 * half + slr) * 64 + l] =
                *(const uint4*)tmp;
        }
    }
}

// ---------------------------------------------------------------------------
// attn_flash14: verified R15/R16 attention body (no setprio, no prefetch).
// ---------------------------------------------------------------------------
__global__ __launch_bounds__(256, 1) void attn_flash14(
    const uint4* __restrict__ qfrag, const uint4* __restrict__ kfrag,
    const uint4* __restrict__ vfrag, float* __restrict__ out, int nb)
{
    __shared__ uint4 Pex[2][512];        // dbuf A-frags, 16 KB
    __shared__ float mlbuf[2][2][4][32]; // [buf][m|l][kq][q], 2 KB

    int qt, b;
    if (nb == 4) {
        const int lin = blockIdx.x;       // 512 blocks = 2/CU
        const int x = lin & 7;            // XCD
        b = x >> 1;                       // 2 XCDs per batch
        const int k = lin >> 3;           // slot k and k+32 share a CU
        const int f = (k < 32) ? k : (95 - k);   // f + f' = 63
        qt = 2 * f + (x & 1);             // [0,128)
    } else { qt = blockIdx.x; b = 0; }    // grid 128

    const size_t pp = (size_t)SEQ * DIM;
    const uint4* qfb = qfrag + (size_t)b * 131072;
    const uint4* kfb = kfrag + (size_t)b * 131072;
    const uint4* vfb = vfrag + (size_t)b * 131072;
    float* outb = out + b * pp;

    const int wid = threadIdx.x >> 6, lane = threadIdx.x & 63;
    const int col = lane & 31, hi = lane >> 5;
    const int kq = wid;                   // 32-key quarter / 64-col quarter
    const int q0 = qt * 32;
    const int nt = (qt + 4) >> 2;         // 128-key tiles

    // Q fragments resident, coalesced from qfrag (16 x 1KB)
    f16x8 qhf[16];
    {
        const uint4* qp = qfb + (size_t)(q0 >> 5) * 1024 + lane;
        #pragma unroll
        for (int sl = 0; sl < 16; ++sl)
            qhf[sl] = __builtin_bit_cast(f16x8, qp[sl * 64]);
    }

    float m_run = -1e28f, l_run = 0.f;
    f32x16 oacc[2] = {};                  // cols 64*kq + {col, 32+col}

    for (int t = 0; t < nt; ++t) {
        const int key0 = t << 7;
        const int pb = t & 1;
        const uint4* kp = kfb + (size_t)(4 * t + kq) * 1024 + lane;

        // ---- QK^T: own 32-key quarter (verified 2-chain form) ----
        f32x16 s1 = {}, s2 = {};
        #pragma unroll
        for (int sl = 0; sl < 16; ++sl) {
            const f16x8 kf = __builtin_bit_cast(f16x8, kp[sl * 64]);
            if (sl & 1) s2 = __builtin_amdgcn_mfma_f32_32x32x16_f16(kf, qhf[sl], s2, 0, 0, 0);
            else        s1 = __builtin_amdgcn_mfma_f32_32x32x16_f16(kf, qhf[sl], s1, 0, 0, 0);
        }

        // ---- V prefetch A-half (slices 0..3, own 64-col quarter) ----
        const uint4* vp = vfb + (size_t)(8 * t + 2 * kq) * 512 + lane;
        f16x8 vfA[2][4];
        #pragma unroll
        for (int cg = 0; cg < 2; ++cg)
            #pragma unroll
            for (int s = 0; s < 4; ++s)
                vfA[cg][s] = __builtin_bit_cast(f16x8, vp[cg * 512 + s * 64]);

        // ---- mask + wave-local softmax (verified R10-R16 verbatim) ----
        float sv[16];
        float pmax = -1e30f, tsum = 0.f;
        #pragma unroll
        for (int r = 0; r < 16; ++r) {
            const int kg = key0 + 32 * kq + (r & 3) + 8 * (r >> 2) + 4 * hi;
            const float x = (kg <= q0 + col) ? (s1[r] + s2[r]) : -1e30f;
            sv[r] = x;
            pmax = fmaxf(pmax, x);
        }
        pmax = fmaxf(pmax, __shfl_xor(pmax, 32));
        pmax = fmaxf(pmax, -1e28f);       // fully-masked quarter -> p = 0
        {
            float p[16];
            #pragma unroll
            for (int r = 0; r < 16; ++r) {
                p[r] = exp2f(sv[r] - pmax);
                tsum += p[r];
            }
            tsum += __shfl_xor(tsum, 32);
            // A-frag build (verified cvt_pk + shfl_xor(32))
            uint32_t Wd[8], Od[8];
            #pragma unroll
            for (int jj = 0; jj < 8; ++jj)
                Wd[jj] = __builtin_bit_cast(uint32_t,
                    __builtin_amdgcn_cvt_pkrtz(p[2 * jj], p[2 * jj + 1]));
            #pragma unroll
            for (int jj = 0; jj < 8; ++jj)
                Od[jj] = (uint32_t)__shfl_xor((int)Wd[jj], 32);
            uint4 A0, A1;
            if (hi == 0) {
                A0.x = Wd[0]; A0.y = Wd[1]; A0.z = Od[0]; A0.w = Od[1];
                A1.x = Wd[4]; A1.y = Wd[5]; A1.z = Od[4]; A1.w = Od[5];
            } else {
                A0.x = Od[2]; A0.y = Od[3]; A0.z = Wd[2]; A0.w = Wd[3];
                A1.x = Od[6]; A1.y = Od[7]; A1.z = Wd[6]; A1.w = Wd[7];
            }
            Pex[pb][((2 * kq + 0) * 2 + hi) * 32 + col] = A0;  // keys [32kq,+16)
            Pex[pb][((2 * kq + 1) * 2 + hi) * 32 + col] = A1;  // keys [32kq+16,+16)
        }
        if (lane < 32) {
            mlbuf[pb][0][kq][col] = pmax;
            mlbuf[pb][1][kq][col] = tsum;
        }

        // ---- V prefetch B-half (slices 4..7) BEFORE the barrier ----
        f16x8 vfB[2][4];
        #pragma unroll
        for (int cg = 0; cg < 2; ++cg)
            #pragma unroll
            for (int s = 0; s < 4; ++s)
                vfB[cg][s] = __builtin_bit_cast(f16x8, vp[cg * 512 + (s + 4) * 64]);

        __syncthreads();                  // the ONLY barrier per iter

        // ---- 4-way m/l merge (verified), defer-max rescale ----
        const float mw0 = mlbuf[pb][0][0][col], mw1 = mlbuf[pb][0][1][col];
        const float mw2 = mlbuf[pb][0][2][col], mw3 = mlbuf[pb][0][3][col];
        const float tw0 = mlbuf[pb][1][0][col], tw1 = mlbuf[pb][1][1][col];
        const float tw2 = mlbuf[pb][1][2][col], tw3 = mlbuf[pb][1][3][col];
        const float mt = fmaxf(fmaxf(mw0, mw1), fmaxf(mw2, mw3));
        float scale = 1.f;
        if (__any(mt > m_run + 11.5415603f)) {   // 8-nat window (log2)
            const float m_new = fmaxf(m_run, mt);
            scale = exp2f(m_run - m_new);
            m_run = m_new;
            #pragma unroll
            for (int r = 0; r < 16; ++r) {
                const int qr = (r & 3) + 8 * (r >> 2) + 4 * hi;
                const float scr = __shfl(scale, qr | (lane & 32));
                oacc[0][r] *= scr; oacc[1][r] *= scr;
            }
        }
        const float c0 = exp2f(mw0 - m_run), c1 = exp2f(mw1 - m_run);
        const float c2 = exp2f(mw2 - m_run), c3 = exp2f(mw3 - m_run);
        l_run = l_run * scale + tw0 * c0 + tw1 * c1 + tw2 * c2 + tw3 * c3;
        const f16 ch[4] = {(f16)c0, (f16)c1, (f16)c2, (f16)c3};

        // ---- PV: 8 slices x own 64-col quarter (V in regs) ----
        #pragma unroll
        for (int s4 = 0; s4 < 4; ++s4) {
            f16x8 af = __builtin_bit_cast(f16x8, Pex[pb][(s4 * 2 + hi) * 32 + col]);
            af = af * ch[s4 >> 1];
            oacc[0] = __builtin_amdgcn_mfma_f32_32x32x16_f16(af, vfA[0][s4], oacc[0], 0, 0, 0);
            oacc[1] = __builtin_amdgcn_mfma_f32_32x32x16_f16(af, vfA[1][s4], oacc[1], 0, 0, 0);
        }
        #pragma unroll
        for (int s4 = 0; s4 < 4; ++s4) {
            f16x8 af = __builtin_bit_cast(f16x8, Pex[pb][((s4 + 4) * 2 + hi) * 32 + col]);
            af = af * ch[2 + (s4 >> 1)];
            oacc[0] = __builtin_amdgcn_mfma_f32_32x32x16_f16(af, vfB[0][s4], oacc[0], 0, 0, 0);
            oacc[1] = __builtin_amdgcn_mfma_f32_32x32x16_f16(af, vfB[1][s4], oacc[1], 0, 0, 0);
        }
        // dbuf: next iter writes Pex[pb^1]/mlbuf[pb^1]; laggard's reads of
        // Pex[pb] are safe; barrier(t+1) orders reuse of Pex[pb] at t+2.
    }

    // ---- epilogue: divide by l, store fp32 ----
    const float linv = 1.f / l_run;
    #pragma unroll
    for (int r = 0; r < 16; ++r) {
        const int qr = (r & 3) + 8 * (r >> 2) + 4 * hi;
        const float lr = __shfl(linv, qr | (lane & 32));
        const int n = q0 + qr;
        outb[(size_t)n * DIM + 64 * kq + col]      = oacc[0][r] * lr;
        outb[(size_t)n * DIM + 64 * kq + 32 + col] = oacc[1][r] * lr;
    }
}

// ---------------------------------------------------------------------------
extern "C" void kernel_launch(void* const* d_in, const int* in_sizes, int n_in,
                              void* d_out, int out_size, void* d_ws, size_t ws_size,
                              hipStream_t stream) {
    const float* x  = (const float*)d_in[0];
    const float* Wq = (const float*)d_in[1];
    const float* bq = (const float*)d_in[2];
    const float* Wk = (const float*)d_in[3];
    const float* bk = (const float*)d_in[4];
    const float* Wv = (const float*)d_in[5];
    const float* bv = (const float*)d_in[6];
    float* out = (float*)d_out;

    const size_t PP = (size_t)SEQ * DIM;            // 1M elems per batch plane
    const size_t FULL = 4 * PP;                     // 4M elems (8 MB fp16)
    const size_t WSZ = (size_t)DIM * DIM;           // 64K elems per W plane

    if (ws_size >= FULL * 2 * 5) {                  // known-true threshold
        f16* qfr = (f16*)d_ws;                      // Q fragment plane (8 MB)
        f16* kfr = qfr + FULL;                      // K fragment plane (8 MB)
        f16* vfr = kfr + FULL;                      // V fragment plane (8 MB)
        f16* whq = vfr + FULL;                      // 3 x 64K fp16 = 384 KB
        f16* whk = whq + WSZ;
        f16* whv = whk + WSZ;

        wsplit_h<<<dim3(256, 3), 256, 0, stream>>>(Wq, Wk, Wv, whq, whk, whv);
        proj3<<<dim3(256, 3), 256, 0, stream>>>(
            x, whq, bq, whk, bk, whv, bv, qfr, kfr, vfr);
        attn_flash14<<<dim3(512), 256, 0, stream>>>(
            (const uint4*)qfr, (const uint4*)kfr, (const uint4*)vfr, out, 4);
    } else {
        // per-batch fallback
        f16* qfr = (f16*)d_ws;
        f16* kfr = qfr + PP;
        f16* vfr = kfr + PP;
        f16* whq = vfr + PP;
        f16* whk = whq + WSZ;
        f16* whv = whk + WSZ;

        wsplit_h<<<dim3(256, 3), 256, 0, stream>>>(Wq, Wk, Wv, whq, whk, whv);
        for (int b = 0; b < 4; ++b) {
            const float* xb = x + b * PP;
            proj3<<<dim3(64, 3), 256, 0, stream>>>(
                xb, whq, bq, whk, bk, whv, bv, qfr, kfr, vfr);
            attn_flash14<<<dim3(128), 256, 0, stream>>>(
                (const uint4*)qfr, (const uint4*)kfr, (const uint4*)vfr, out + b * PP, 1);
        }
    }
}